// Round 1
// baseline (2419.354 us; speedup 1.0000x reference)
//
#include <hip/hip_runtime.h>
#include <hip/hip_bf16.h>
#include <cstdint>
#include <cstddef>

// Problem constants
#define Bdim 2
#define Tdim 2048
#define Ddim 2048
#define NHq  16      // query heads
#define NKV  4       // kv heads
#define HD   128     // head dim
#define SCALE 0.08838834764831845f  // 1/sqrt(128)

__device__ __forceinline__ unsigned short f2bf(float f) {
    unsigned int u = __float_as_uint(f);
    u += 0x7FFFu + ((u >> 16) & 1u);   // round-to-nearest-even
    return (unsigned short)(u >> 16);
}
__device__ __forceinline__ float bf2f(unsigned short s) {
    return __uint_as_float(((unsigned int)s) << 16);
}

// ---------------------------------------------------------------------------
// 128x128 fp32 SGEMM tile body: C[m0:m0+128][wcol:wcol+128] = A[4096xK=2048] @ W[2048xldw]
// 256 threads, 8x8 acc per thread, BK=16, transposed-A LDS.
// out leading dim == ldw for all users.
// ---------------------------------------------------------------------------
__device__ __forceinline__ void gemm_tile_body(const float* __restrict__ A,
                                               const float* __restrict__ W,
                                               float* __restrict__ out,
                                               int m0, int wcol, int ldw,
                                               float (&Ast)[16][132],
                                               float (&Bs)[16][132])
{
    const int tid = threadIdx.x;
    const int ty = tid >> 4, tx = tid & 15;
    const int arow   = tid >> 2;          // 0..63 (two halves -> 128 rows)
    const int achunk = (tid & 3) * 4;     // k-chunk of 4
    const int brow   = tid >> 5;          // 0..7 (two halves -> 16 k rows)
    const int bcol   = (tid & 31) * 4;    // col chunk of 4

    float acc[8][8];
#pragma unroll
    for (int i = 0; i < 8; i++)
#pragma unroll
        for (int j = 0; j < 8; j++) acc[i][j] = 0.f;

    for (int k0 = 0; k0 < 2048; k0 += 16) {
#pragma unroll
        for (int half = 0; half < 2; half++) {
            int r = arow + half * 64;
            float4 av = *(const float4*)(A + (size_t)(m0 + r) * Ddim + k0 + achunk);
            Ast[achunk + 0][r] = av.x;
            Ast[achunk + 1][r] = av.y;
            Ast[achunk + 2][r] = av.z;
            Ast[achunk + 3][r] = av.w;
        }
#pragma unroll
        for (int half = 0; half < 2; half++) {
            int kr = brow + half * 8;
            *(float4*)&Bs[kr][bcol] =
                *(const float4*)(W + (size_t)(k0 + kr) * ldw + wcol + bcol);
        }
        __syncthreads();
#pragma unroll
        for (int kk = 0; kk < 16; kk++) {
            float4 a0 = *(const float4*)&Ast[kk][ty * 4];
            float4 a1 = *(const float4*)&Ast[kk][64 + ty * 4];
            float4 b0 = *(const float4*)&Bs[kk][tx * 4];
            float4 b1 = *(const float4*)&Bs[kk][64 + tx * 4];
            float av[8] = {a0.x, a0.y, a0.z, a0.w, a1.x, a1.y, a1.z, a1.w};
            float bv[8] = {b0.x, b0.y, b0.z, b0.w, b1.x, b1.y, b1.z, b1.w};
#pragma unroll
            for (int i = 0; i < 8; i++)
#pragma unroll
                for (int j = 0; j < 8; j++)
                    acc[i][j] = fmaf(av[i], bv[j], acc[i][j]);
        }
        __syncthreads();
    }
#pragma unroll
    for (int i = 0; i < 8; i++) {
        int r = m0 + ((i < 4) ? (ty * 4 + i) : (64 + ty * 4 + (i - 4)));
        float4 o0 = make_float4(acc[i][0], acc[i][1], acc[i][2], acc[i][3]);
        float4 o1 = make_float4(acc[i][4], acc[i][5], acc[i][6], acc[i][7]);
        *(float4*)(out + (size_t)r * ldw + wcol + tx * 4) = o0;
        *(float4*)(out + (size_t)r * ldw + wcol + 64 + tx * 4) = o1;
    }
}

// Fused QKV projection: grid (24, 32). Column tiles: [0,16)=Q, [16,20)=K, [20,24)=V.
__global__ __launch_bounds__(256) void qkv_gemm(const float* __restrict__ Xq,
                                                const float* __restrict__ Xkv,
                                                const float* __restrict__ Wq,
                                                const float* __restrict__ Wk,
                                                const float* __restrict__ Wv,
                                                float* __restrict__ qo,
                                                float* __restrict__ ko,
                                                float* __restrict__ vo)
{
    __shared__ float Ast[16][132];
    __shared__ float Bs[16][132];
    const int colBase = blockIdx.x * 128;
    const int m0 = blockIdx.y * 128;
    const float* A; const float* W; float* out; int ldw; int wcol;
    if (colBase < 2048)      { A = Xq;  W = Wq; out = qo; ldw = 2048; wcol = colBase; }
    else if (colBase < 2560) { A = Xkv; W = Wk; out = ko; ldw = 512;  wcol = colBase - 2048; }
    else                     { A = Xkv; W = Wv; out = vo; ldw = 512;  wcol = colBase - 2560; }
    gemm_tile_body(A, W, out, m0, wcol, ldw, Ast, Bs);
}

// Output projection: grid (16, 32). out = attn[4096x2048] @ Wo[2048x2048]
__global__ __launch_bounds__(256) void oproj_gemm(const float* __restrict__ attn,
                                                  const float* __restrict__ Wo,
                                                  float* __restrict__ out)
{
    __shared__ float Ast[16][132];
    __shared__ float Bs[16][132];
    gemm_tile_body(attn, Wo, out, blockIdx.y * 128, blockIdx.x * 128, 2048, Ast, Bs);
}

// In-place RoPE on q and k buffers. One thread per (row, h<64) pair.
__global__ __launch_bounds__(256) void rope_kernel(float* __restrict__ q,
                                                   float* __restrict__ k,
                                                   const int* __restrict__ qpos,
                                                   const int* __restrict__ kvpos)
{
    const long long qPairs = (long long)Bdim * Tdim * NHq * 64;  // 4,194,304
    const long long kPairs = (long long)Bdim * Tdim * NKV * 64;  // 1,048,576
    long long idx = (long long)blockIdx.x * 256 + threadIdx.x;
    if (idx >= qPairs + kPairs) return;
    float* base; int h; int pos;
    if (idx < qPairs) {
        h = (int)(idx & 63);
        long long rn = idx >> 6;          // (b*T+t)*NHq + n
        pos = qpos[rn / NHq];
        base = q + rn * HD;
    } else {
        long long j2 = idx - qPairs;
        h = (int)(j2 & 63);
        long long rn = j2 >> 6;           // (b*T+t)*NKV + kvh
        pos = kvpos[rn / NKV];
        base = k + rn * HD;
    }
    // timescale = 10000^(h/64);  ln(10000)/64 = 0.14391156831
    float inv_ts = expf(-(float)h * 0.14391156831f);
    float ang = (float)pos * inv_ts;
    float s, c;
    sincosf(ang, &s, &c);
    float x1 = base[h], x2 = base[h + 64];
    base[h]      = x1 * c - x2 * s;
    base[h + 64] = x2 * c + x1 * s;
}

// ---------------------------------------------------------------------------
// Flash attention, causal, GQA (q head n uses kv head n>>2).
// Grid (32 qtiles, 32 b*heads), 256 threads. BQ=BKV=64.
// Q/K transposed bf16 in LDS, V/P bf16, softmax state fp32.
// ---------------------------------------------------------------------------
__global__ __launch_bounds__(256) void flash_attn(const float* __restrict__ q,
                                                  const float* __restrict__ k,
                                                  const float* __restrict__ v,
                                                  float* __restrict__ attn)
{
    __shared__ unsigned short Qt[128][68];   // [kk][row]
    __shared__ unsigned short Kt[128][68];   // [kk][col]
    __shared__ unsigned short Vs[64][132];   // [srow][h]
    __shared__ unsigned short Ps[64][68];    // probs bf16
    __shared__ float mArr[64], lArr[64], aArr[64];

    const int qt = (int)gridDim.x - 1 - (int)blockIdx.x;  // big workloads first
    const int bh = blockIdx.y;
    const int b = bh >> 4, n = bh & 15;
    const int kvh = n >> 2;
    const int q0 = qt * 64;
    const int tid = threadIdx.x;
    const int ty = tid >> 4, tx = tid & 15;   // 16x16 thread grid

    float O[4][8];
#pragma unroll
    for (int i = 0; i < 4; i++)
#pragma unroll
        for (int c = 0; c < 8; c++) O[i][c] = 0.f;
    if (tid < 64) { mArr[tid] = -3.0e38f; lArr[tid] = 0.f; }

    // Load Q tile (transposed, bf16)
    for (int i = tid; i < 64 * 32; i += 256) {
        int r = i >> 5, c4 = (i & 31) * 4;
        float4 qv = *(const float4*)(q + ((size_t)(b * Tdim + q0 + r) * NHq + n) * HD + c4);
        Qt[c4 + 0][r] = f2bf(qv.x);
        Qt[c4 + 1][r] = f2bf(qv.y);
        Qt[c4 + 2][r] = f2bf(qv.z);
        Qt[c4 + 3][r] = f2bf(qv.w);
    }

    const int nT = qt + 1;
    for (int t = 0; t < nT; t++) {
        const int s0 = t * 64;
        __syncthreads();   // protect Kt/Vs from previous iteration's readers
        for (int i = tid; i < 64 * 32; i += 256) {
            int r = i >> 5, c4 = (i & 31) * 4;
            size_t gofs = ((size_t)(b * Tdim + s0 + r) * NKV + kvh) * HD + c4;
            float4 kv4 = *(const float4*)(k + gofs);
            Kt[c4 + 0][r] = f2bf(kv4.x);
            Kt[c4 + 1][r] = f2bf(kv4.y);
            Kt[c4 + 2][r] = f2bf(kv4.z);
            Kt[c4 + 3][r] = f2bf(kv4.w);
            float4 vv4 = *(const float4*)(v + gofs);
            ushort4 vw;
            vw.x = f2bf(vv4.x); vw.y = f2bf(vv4.y);
            vw.z = f2bf(vv4.z); vw.w = f2bf(vv4.w);
            *(ushort4*)&Vs[r][c4] = vw;
        }
        __syncthreads();

        // S = Q K^T  (rows ty*4.., cols tx*4..)
        float sa[4][4];
#pragma unroll
        for (int i = 0; i < 4; i++)
#pragma unroll
            for (int j = 0; j < 4; j++) sa[i][j] = 0.f;
#pragma unroll 4
        for (int kk = 0; kk < HD; kk++) {
            ushort4 aw = *(const ushort4*)&Qt[kk][ty * 4];
            ushort4 bw = *(const ushort4*)&Kt[kk][tx * 4];
            float av[4] = {bf2f(aw.x), bf2f(aw.y), bf2f(aw.z), bf2f(aw.w)};
            float bv[4] = {bf2f(bw.x), bf2f(bw.y), bf2f(bw.z), bf2f(bw.w)};
#pragma unroll
            for (int i = 0; i < 4; i++)
#pragma unroll
                for (int j = 0; j < 4; j++)
                    sa[i][j] = fmaf(av[i], bv[j], sa[i][j]);
        }

        // In-register online softmax; row stats reduced over the 16 tx lanes
        // (same wave as readers; same-wave LDS ordering makes barrier-free OK).
#pragma unroll
        for (int i = 0; i < 4; i++) {
            const int r = ty * 4 + i;
            const int gi = q0 + r;
            float sv[4];
#pragma unroll
            for (int j = 0; j < 4; j++) {
                int gj = s0 + tx * 4 + j;
                sv[j] = (gj <= gi) ? sa[i][j] * SCALE : -3.0e38f;
            }
            float mloc = fmaxf(fmaxf(sv[0], sv[1]), fmaxf(sv[2], sv[3]));
            mloc = fmaxf(mloc, __shfl_xor(mloc, 1));
            mloc = fmaxf(mloc, __shfl_xor(mloc, 2));
            mloc = fmaxf(mloc, __shfl_xor(mloc, 4));
            mloc = fmaxf(mloc, __shfl_xor(mloc, 8));
            float mOld = mArr[r];
            float mNew = fmaxf(mOld, mloc);
            float p0 = __expf(sv[0] - mNew);
            float p1 = __expf(sv[1] - mNew);
            float p2 = __expf(sv[2] - mNew);
            float p3 = __expf(sv[3] - mNew);
            ushort4 pw;
            pw.x = f2bf(p0); pw.y = f2bf(p1); pw.z = f2bf(p2); pw.w = f2bf(p3);
            *(ushort4*)&Ps[r][tx * 4] = pw;
            float ps = p0 + p1 + p2 + p3;
            ps += __shfl_xor(ps, 1);
            ps += __shfl_xor(ps, 2);
            ps += __shfl_xor(ps, 4);
            ps += __shfl_xor(ps, 8);
            if (tx == 0) {
                float alpha = __expf(mOld - mNew);
                mArr[r] = mNew;
                lArr[r] = lArr[r] * alpha + ps;
                aArr[r] = alpha;
            }
        }

        // PV accumulate: rows ty*4.., cols tx*8..
#pragma unroll
        for (int i = 0; i < 4; i++) {
            float alpha = aArr[ty * 4 + i];
#pragma unroll
            for (int c = 0; c < 8; c++) O[i][c] *= alpha;
        }
        for (int j = 0; j < 64; j++) {
            ushort4 vw0 = *(const ushort4*)&Vs[j][tx * 8];
            ushort4 vw1 = *(const ushort4*)&Vs[j][tx * 8 + 4];
            float vv[8] = {bf2f(vw0.x), bf2f(vw0.y), bf2f(vw0.z), bf2f(vw0.w),
                           bf2f(vw1.x), bf2f(vw1.y), bf2f(vw1.z), bf2f(vw1.w)};
#pragma unroll
            for (int i = 0; i < 4; i++) {
                float p = bf2f(Ps[ty * 4 + i][j]);
#pragma unroll
                for (int c = 0; c < 8; c++) O[i][c] = fmaf(p, vv[c], O[i][c]);
            }
        }
    }

    // Epilogue: normalize and write attn[b][t][n][h]
#pragma unroll
    for (int i = 0; i < 4; i++) {
        int r = ty * 4 + i;
        float inv = 1.0f / lArr[r];
        float4 o0 = make_float4(O[i][0] * inv, O[i][1] * inv, O[i][2] * inv, O[i][3] * inv);
        float4 o1 = make_float4(O[i][4] * inv, O[i][5] * inv, O[i][6] * inv, O[i][7] * inv);
        float* dst = attn + ((size_t)(b * Tdim + q0 + r) * NHq + n) * HD + tx * 8;
        *(float4*)dst = o0;
        *(float4*)(dst + 4) = o1;
    }
}

extern "C" void kernel_launch(void* const* d_in, const int* in_sizes, int n_in,
                              void* d_out, int out_size, void* d_ws, size_t ws_size,
                              hipStream_t stream) {
    const float* Xq   = (const float*)d_in[0];
    const float* Xkv  = (const float*)d_in[1];
    const int*   qpos = (const int*)d_in[2];
    const int*   kvpos= (const int*)d_in[3];
    const float* Wq   = (const float*)d_in[4];
    const float* Wk   = (const float*)d_in[5];
    const float* Wv   = (const float*)d_in[6];
    const float* Wo   = (const float*)d_in[7];
    float* out = (float*)d_out;

    float* ws = (float*)d_ws;
    float* qb = ws;                                   // 4096 x 2048
    float* kb = qb + (size_t)4096 * 2048;             // 4096 x 512
    float* vb = kb + (size_t)4096 * 512;              // 4096 x 512
    float* ab = vb + (size_t)4096 * 512;              // 4096 x 2048

    qkv_gemm<<<dim3(24, 32), 256, 0, stream>>>(Xq, Xkv, Wq, Wk, Wv, qb, kb, vb);
    rope_kernel<<<20480, 256, 0, stream>>>(qb, kb, qpos, kvpos);
    flash_attn<<<dim3(32, 32), 256, 0, stream>>>(qb, kb, vb, ab);
    oproj_gemm<<<dim3(16, 32), 256, 0, stream>>>(ab, Wo, out);
}

// Round 2
// 1559.339 us; speedup vs baseline: 1.5515x; 1.5515x over previous
//
#include <hip/hip_runtime.h>
#include <hip/hip_bf16.h>
#include <cstdint>
#include <cstddef>

#define Bdim 2
#define Tdim 2048
#define Ddim 2048
#define NHq  16
#define NKV  4
#define HD   128
#define SCALE 0.08838834764831845f
#define NEG_INF (-3.0e38f)

typedef unsigned short u16;
typedef __bf16 bf16x8 __attribute__((ext_vector_type(8)));
typedef float  f32x4  __attribute__((ext_vector_type(4)));

__device__ __forceinline__ u16 f2bf(float f) {
    unsigned int u = __float_as_uint(f);
    u += 0x7FFFu + ((u >> 16) & 1u);   // RNE
    return (u16)(u >> 16);
}

// ---------------------------------------------------------------------------
// fp32 SGEMM mainloop (128x128 tile, 256 thr, 8x8 acc, BK=16). Epilogue in caller.
// ---------------------------------------------------------------------------
__device__ __forceinline__ void gemm_mainloop(const float* __restrict__ A,
                                              const float* __restrict__ W,
                                              int m0, int wcol, int ldw,
                                              float (&acc)[8][8],
                                              float (&Ast)[16][132],
                                              float (&Bs)[16][132])
{
    const int tid = threadIdx.x;
    const int ty = tid >> 4, tx = tid & 15;
    const int arow   = tid >> 2;
    const int achunk = (tid & 3) * 4;
    const int brow   = tid >> 5;
    const int bcol   = (tid & 31) * 4;

#pragma unroll
    for (int i = 0; i < 8; i++)
#pragma unroll
        for (int j = 0; j < 8; j++) acc[i][j] = 0.f;

    for (int k0 = 0; k0 < 2048; k0 += 16) {
#pragma unroll
        for (int half = 0; half < 2; half++) {
            int r = arow + half * 64;
            float4 av = *(const float4*)(A + (size_t)(m0 + r) * Ddim + k0 + achunk);
            Ast[achunk + 0][r] = av.x;
            Ast[achunk + 1][r] = av.y;
            Ast[achunk + 2][r] = av.z;
            Ast[achunk + 3][r] = av.w;
        }
#pragma unroll
        for (int half = 0; half < 2; half++) {
            int kr = brow + half * 8;
            *(float4*)&Bs[kr][bcol] =
                *(const float4*)(W + (size_t)(k0 + kr) * ldw + wcol + bcol);
        }
        __syncthreads();
#pragma unroll
        for (int kk = 0; kk < 16; kk++) {
            float4 a0 = *(const float4*)&Ast[kk][ty * 4];
            float4 a1 = *(const float4*)&Ast[kk][64 + ty * 4];
            float4 b0 = *(const float4*)&Bs[kk][tx * 4];
            float4 b1 = *(const float4*)&Bs[kk][64 + tx * 4];
            float av[8] = {a0.x, a0.y, a0.z, a0.w, a1.x, a1.y, a1.z, a1.w};
            float bv[8] = {b0.x, b0.y, b0.z, b0.w, b1.x, b1.y, b1.z, b1.w};
#pragma unroll
            for (int i = 0; i < 8; i++)
#pragma unroll
                for (int j = 0; j < 8; j++)
                    acc[i][j] = fmaf(av[i], bv[j], acc[i][j]);
        }
        __syncthreads();
    }
}

__device__ __forceinline__ void gemm_store_f32(float (&acc)[8][8], float* __restrict__ out,
                                               int m0, int wcol, int ldw)
{
    const int tid = threadIdx.x;
    const int ty = tid >> 4, tx = tid & 15;
#pragma unroll
    for (int i = 0; i < 8; i++) {
        int r = m0 + ((i < 4) ? (ty * 4 + i) : (64 + ty * 4 + (i - 4)));
        float4 o0 = make_float4(acc[i][0], acc[i][1], acc[i][2], acc[i][3]);
        float4 o1 = make_float4(acc[i][4], acc[i][5], acc[i][6], acc[i][7]);
        *(float4*)(out + (size_t)r * ldw + wcol + tx * 4) = o0;
        *(float4*)(out + (size_t)r * ldw + wcol + 64 + tx * 4) = o1;
    }
}

// Q and K projections: grid (20, 32). Cols [0,16)=Q tiles, [16,20)=K tiles.
__global__ __launch_bounds__(256) void qk_gemm(const float* __restrict__ Xq,
                                               const float* __restrict__ Xkv,
                                               const float* __restrict__ Wq,
                                               const float* __restrict__ Wk,
                                               float* __restrict__ qo,
                                               float* __restrict__ ko)
{
    __shared__ float Ast[16][132];
    __shared__ float Bs[16][132];
    const int colBase = blockIdx.x * 128;
    const int m0 = blockIdx.y * 128;
    const float* A; const float* W; float* out; int ldw; int wcol;
    if (colBase < 2048) { A = Xq;  W = Wq; out = qo; ldw = 2048; wcol = colBase; }
    else                { A = Xkv; W = Wk; out = ko; ldw = 512;  wcol = colBase - 2048; }
    float acc[8][8];
    gemm_mainloop(A, W, m0, wcol, ldw, acc, Ast, Bs);
    gemm_store_f32(acc, out, m0, wcol, ldw);
}

// V projection with transposed bf16 output: vtg[(b*NKV+kvh)*HD + h][t]. grid (4, 32).
__global__ __launch_bounds__(256) void v_gemm_t(const float* __restrict__ Xkv,
                                                const float* __restrict__ Wv,
                                                u16* __restrict__ vtg)
{
    __shared__ float Ast[16][132];
    __shared__ float Bs[16][132];
    const int m0 = blockIdx.y * 128;
    const int wcol = blockIdx.x * 128;
    float acc[8][8];
    gemm_mainloop(Xkv, Wv, m0, wcol, 512, acc, Ast, Bs);
    const int tid = threadIdx.x;
    const int ty = tid >> 4, tx = tid & 15;
    const int b = m0 >> 11, t0 = m0 & 2047;
    const int kvh = wcol >> 7;
#pragma unroll
    for (int jj = 0; jj < 8; jj++) {
        int h = (jj < 4) ? (tx * 4 + jj) : (64 + tx * 4 + (jj - 4));
        size_t rowbase = (((size_t)(b * NKV + kvh)) * HD + h) * Tdim;
        ushort4 lo, hi;
        lo.x = f2bf(acc[0][jj]); lo.y = f2bf(acc[1][jj]);
        lo.z = f2bf(acc[2][jj]); lo.w = f2bf(acc[3][jj]);
        hi.x = f2bf(acc[4][jj]); hi.y = f2bf(acc[5][jj]);
        hi.z = f2bf(acc[6][jj]); hi.w = f2bf(acc[7][jj]);
        *(ushort4*)(vtg + rowbase + t0 + ty * 4) = lo;
        *(ushort4*)(vtg + rowbase + t0 + 64 + ty * 4) = hi;
    }
}

// Output projection: grid (16, 32).
__global__ __launch_bounds__(256) void oproj_gemm(const float* __restrict__ attn,
                                                  const float* __restrict__ Wo,
                                                  float* __restrict__ out)
{
    __shared__ float Ast[16][132];
    __shared__ float Bs[16][132];
    float acc[8][8];
    gemm_mainloop(attn, Wo, blockIdx.y * 128, blockIdx.x * 128, 2048, acc, Ast, Bs);
    gemm_store_f32(acc, out, blockIdx.y * 128, blockIdx.x * 128, 2048);
}

// RoPE: read fp32 q/k, write bf16 q/k. One thread per (row, h<64) pair.
__global__ __launch_bounds__(256) void rope_convert(const float* __restrict__ qb,
                                                    const float* __restrict__ kb,
                                                    const int* __restrict__ qpos,
                                                    const int* __restrict__ kvpos,
                                                    u16* __restrict__ qh,
                                                    u16* __restrict__ kh)
{
    const long long qPairs = (long long)Bdim * Tdim * NHq * 64;  // 4,194,304
    const long long kPairs = (long long)Bdim * Tdim * NKV * 64;  // 1,048,576
    long long idx = (long long)blockIdx.x * 256 + threadIdx.x;
    if (idx >= qPairs + kPairs) return;
    const float* src; u16* dst; int h; int pos;
    if (idx < qPairs) {
        h = (int)(idx & 63);
        long long rn = idx >> 6;
        pos = qpos[rn / NHq];
        src = qb + rn * HD; dst = qh + rn * HD;
    } else {
        long long j2 = idx - qPairs;
        h = (int)(j2 & 63);
        long long rn = j2 >> 6;
        pos = kvpos[rn / NKV];
        src = kb + rn * HD; dst = kh + rn * HD;
    }
    float inv_ts = expf(-(float)h * 0.14391156831f);  // 10000^(-h/64)
    float ang = (float)pos * inv_ts;
    float s, c;
    sincosf(ang, &s, &c);
    float x1 = src[h], x2 = src[h + 64];
    dst[h]      = f2bf(x1 * c - x2 * s);
    dst[h + 64] = f2bf(x2 * c + x1 * s);
}

// ---------------------------------------------------------------------------
// MFMA flash attention. Grid (32 qtiles, 32 b*heads), 256 thr (4 waves).
// BQ=BKV=64; wave w owns M-strip w*16..w*16+15; softmax state in registers.
// XOR-swizzled bf16 LDS tiles; P does C/D->A-layout LDS round trip (same-wave).
// ---------------------------------------------------------------------------
__global__ __launch_bounds__(256) void flash_attn_mfma(const u16* __restrict__ qh,
                                                       const u16* __restrict__ kh,
                                                       const u16* __restrict__ vt,
                                                       float* __restrict__ attn)
{
    // Ks[s][h]: block cb = (h>>3) ^ (s&7), addr = s*128 + cb*8 + (h&7)
    __shared__ __align__(16) u16 Ks[64 * 128];
    // Vt[h][s]: block cb = (s>>3) ^ (h&7), addr = h*64 + cb*8 + (s&7)
    __shared__ __align__(16) u16 Vt[128 * 64];
    // QP: Q staging (rows m, 128 cols, swizzled) then reused as Ps[m][s] (64 cols)
    __shared__ __align__(16) u16 QP[64 * 128];

    const int qt = 31 - (int)blockIdx.x;   // large workloads first
    const int bh = blockIdx.y;
    const int b = bh >> 4, n = bh & 15, kvh = n >> 2;
    const int q0 = qt * 64;
    const int tid = threadIdx.x;
    const int wv = tid >> 6;
    const int lane = tid & 63;
    const int l15 = lane & 15, quad = lane >> 4;

    // ---- stage Q tile (bf16, swizzled) ----
    {
        const size_t qbase = (((size_t)(b * Tdim + q0)) * NHq + n) * HD;
        const int mrow_ = tid >> 4, c8 = tid & 15;
#pragma unroll
        for (int p = 0; p < 4; p++) {
            int m = p * 16 + mrow_;
            bf16x8 qv = *(const bf16x8*)(qh + qbase + (size_t)m * (NHq * HD) + c8 * 8);
            int cb = c8 ^ (m & 7);
            *(bf16x8*)&QP[m * 128 + cb * 8] = qv;
        }
    }
    __syncthreads();

    // ---- Q a-frags to registers (held across KV loop) ----
    bf16x8 qfrag[4];
    {
        int m = wv * 16 + l15;
#pragma unroll
        for (int kt = 0; kt < 4; kt++) {
            int cb = (kt * 4 + quad) ^ (m & 7);
            qfrag[kt] = *(const bf16x8*)&QP[m * 128 + cb * 8];
        }
    }

    f32x4 Oacc[8];
#pragma unroll
    for (int ht = 0; ht < 8; ht++) Oacc[ht] = (f32x4){0.f, 0.f, 0.f, 0.f};
    float mrow[4] = {NEG_INF, NEG_INF, NEG_INF, NEG_INF};
    float lrow[4] = {0.f, 0.f, 0.f, 0.f};

    const size_t kbase = (((size_t)(b * Tdim)) * NKV + kvh) * HD;
    const size_t vbase = ((size_t)(b * NKV + kvh)) * HD * Tdim;

    for (int t = 0; t <= qt; t++) {
        const int s0 = t * 64;
        __syncthreads();   // protect Ks/Vt (and Qs reads on t==0) from overwrite
        {
            const int r16 = tid >> 4, c8 = tid & 15;
#pragma unroll
            for (int p = 0; p < 4; p++) {
                int s = p * 16 + r16;
                bf16x8 kv = *(const bf16x8*)(kh + kbase + (size_t)(s0 + s) * (NKV * HD) + c8 * 8);
                int cb = c8 ^ (s & 7);
                *(bf16x8*)&Ks[s * 128 + cb * 8] = kv;
            }
            const int h8 = tid >> 3, sb = tid & 7;
#pragma unroll
            for (int p = 0; p < 4; p++) {
                int h = p * 32 + h8;
                bf16x8 vv = *(const bf16x8*)(vt + vbase + (size_t)h * Tdim + s0 + sb * 8);
                int cb = sb ^ (h & 7);
                *(bf16x8*)&Vt[h * 64 + cb * 8] = vv;
            }
        }
        __syncthreads();

        // ---- S = Q K^T ----
        f32x4 S[4];
#pragma unroll
        for (int nt = 0; nt < 4; nt++) S[nt] = (f32x4){0.f, 0.f, 0.f, 0.f};
#pragma unroll
        for (int kt = 0; kt < 4; kt++) {
#pragma unroll
            for (int nt = 0; nt < 4; nt++) {
                int sl = nt * 16 + l15;
                int cb = (kt * 4 + quad) ^ (l15 & 7);
                bf16x8 bfrg = *(const bf16x8*)&Ks[sl * 128 + cb * 8];
                S[nt] = __builtin_amdgcn_mfma_f32_16x16x32_bf16(qfrag[kt], bfrg, S[nt], 0, 0, 0);
            }
        }

        // ---- online softmax (register state; rows owned exclusively per wave) ----
        const bool masked = (t == qt);
#pragma unroll
        for (int r = 0; r < 4; r++) {
            const int ml = wv * 16 + quad * 4 + r;
            float sv[4];
            float mx = NEG_INF;
#pragma unroll
            for (int nt = 0; nt < 4; nt++) {
                float vvv = S[nt][r] * SCALE;
                if (masked && (nt * 16 + l15 > ml)) vvv = NEG_INF;
                sv[nt] = vvv;
                mx = fmaxf(mx, vvv);
            }
            mx = fmaxf(mx, __shfl_xor(mx, 1));
            mx = fmaxf(mx, __shfl_xor(mx, 2));
            mx = fmaxf(mx, __shfl_xor(mx, 4));
            mx = fmaxf(mx, __shfl_xor(mx, 8));
            float mNew = fmaxf(mrow[r], mx);
            float alpha = __expf(mrow[r] - mNew);
            mrow[r] = mNew;
            float ps = 0.f;
#pragma unroll
            for (int nt = 0; nt < 4; nt++) {
                float p = __expf(sv[nt] - mNew);
                sv[nt] = p;
                ps += p;
            }
            ps += __shfl_xor(ps, 1);
            ps += __shfl_xor(ps, 2);
            ps += __shfl_xor(ps, 4);
            ps += __shfl_xor(ps, 8);
            lrow[r] = lrow[r] * alpha + ps;
#pragma unroll
            for (int ht = 0; ht < 8; ht++) Oacc[ht][r] *= alpha;
            // write P row (bf16) to Ps region of QP — same-wave rows only
            const int m = ml;
#pragma unroll
            for (int nt = 0; nt < 4; nt++) {
                int s = nt * 16 + l15;
                int cb = (s >> 3) ^ (m & 7);
                QP[m * 64 + cb * 8 + (s & 7)] = f2bf(sv[nt]);
            }
        }

        // ---- P a-frags (same-wave LDS round trip, in-order DS pipe) ----
        bf16x8 pfrag[2];
        {
            int m = wv * 16 + l15;
#pragma unroll
            for (int k2 = 0; k2 < 2; k2++) {
                int cb = (k2 * 4 + quad) ^ (m & 7);
                pfrag[k2] = *(const bf16x8*)&QP[m * 64 + cb * 8];
            }
        }

        // ---- O += P V ----
#pragma unroll
        for (int k2 = 0; k2 < 2; k2++) {
#pragma unroll
            for (int ht = 0; ht < 8; ht++) {
                int h = ht * 16 + l15;
                int cb = (k2 * 4 + quad) ^ (l15 & 7);
                bf16x8 vfrg = *(const bf16x8*)&Vt[h * 64 + cb * 8];
                Oacc[ht] = __builtin_amdgcn_mfma_f32_16x16x32_bf16(pfrag[k2], vfrg, Oacc[ht], 0, 0, 0);
            }
        }
    }

    // ---- epilogue: normalize, write attn[b][t][n][h] fp32 ----
#pragma unroll
    for (int r = 0; r < 4; r++) {
        float inv = 1.0f / lrow[r];
        int mg = q0 + wv * 16 + quad * 4 + r;
        float* dst = attn + (((size_t)(b * Tdim + mg)) * NHq + n) * HD + l15;
#pragma unroll
        for (int ht = 0; ht < 8; ht++) {
            dst[ht * 16] = Oacc[ht][r] * inv;
        }
    }
}

extern "C" void kernel_launch(void* const* d_in, const int* in_sizes, int n_in,
                              void* d_out, int out_size, void* d_ws, size_t ws_size,
                              hipStream_t stream) {
    const float* Xq    = (const float*)d_in[0];
    const float* Xkv   = (const float*)d_in[1];
    const int*   qpos  = (const int*)d_in[2];
    const int*   kvpos = (const int*)d_in[3];
    const float* Wq    = (const float*)d_in[4];
    const float* Wk    = (const float*)d_in[5];
    const float* Wv    = (const float*)d_in[6];
    const float* Wo    = (const float*)d_in[7];
    float* out = (float*)d_out;

    char* w = (char*)d_ws;
    float* qb = (float*)w;                               // 32 MB: q proj fp32
    float* kb = (float*)(w + (32u << 20));               //  8 MB: k proj fp32
    u16*   vt = (u16*)(w + (40u << 20));                 //  4 MB: V^T bf16 [b,kvh,h][t]
    u16*   qh = (u16*)(w + (44u << 20));                 // 16 MB: q roped bf16
    u16*   kh = (u16*)(w + (60u << 20));                 //  4 MB: k roped bf16
    float* ab = qb;                                      // 32 MB: attn out fp32 (reuse qb)

    qk_gemm<<<dim3(20, 32), 256, 0, stream>>>(Xq, Xkv, Wq, Wk, qb, kb);
    v_gemm_t<<<dim3(4, 32), 256, 0, stream>>>(Xkv, Wv, vt);
    rope_convert<<<20480, 256, 0, stream>>>(qb, kb, qpos, kvpos, qh, kh);
    flash_attn_mfma<<<dim3(32, 32), 256, 0, stream>>>(qh, kh, vt, ab);
    oproj_gemm<<<dim3(16, 32), 256, 0, stream>>>(ab, Wo, out);
}

// Round 3
// 483.972 us; speedup vs baseline: 4.9990x; 3.2220x over previous
//
#include <hip/hip_runtime.h>
#include <hip/hip_bf16.h>
#include <cstdint>
#include <cstddef>

#define Bdim 2
#define Tdim 2048
#define Ddim 2048
#define NHq  16
#define NKV  4
#define HD   128
#define SCALE 0.08838834764831845f
#define NEG_INF (-3.0e38f)

typedef unsigned short u16;
typedef unsigned int   u32;
typedef __bf16 bf16x8 __attribute__((ext_vector_type(8)));
typedef float  f32x4  __attribute__((ext_vector_type(4)));

__device__ __forceinline__ u16 f2bf(float f) {
    unsigned int u = __float_as_uint(f);
    u += 0x7FFFu + ((u >> 16) & 1u);   // RNE
    return (u16)(u >> 16);
}
__device__ __forceinline__ float bf2f(u16 s) {
    return __uint_as_float(((unsigned int)s) << 16);
}

// async global->LDS, 16B per lane. LDS dest is wave-uniform base + lane*16.
typedef __attribute__((address_space(1))) const u32 gbl_u32;
typedef __attribute__((address_space(3))) u32 lds_u32;
__device__ __forceinline__ void gload16(const void* g, void* l) {
    __builtin_amdgcn_global_load_lds((gbl_u32*)(uintptr_t)g, (lds_u32*)(uintptr_t)l, 16, 0, 0);
}

// ---------------------------------------------------------------------------
// fp32 -> bf16 straight convert for Xq, Xkv. 8 elems/thread.
// ---------------------------------------------------------------------------
__global__ __launch_bounds__(256) void cvt_x(const float* __restrict__ Xq,
                                             const float* __restrict__ Xkv,
                                             u16* __restrict__ oq,
                                             u16* __restrict__ okv)
{
    const size_t NE = (size_t)4096 * 2048 / 8;   // groups per tensor
    size_t idx = (size_t)blockIdx.x * 256 + threadIdx.x;
    const float* src; u16* dst; size_t off;
    if (idx < NE) { src = Xq;  dst = oq;  off = idx * 8; }
    else          { src = Xkv; dst = okv; off = (idx - NE) * 8; }
    float4 a = *(const float4*)&src[off];
    float4 b = *(const float4*)&src[off + 4];
    ushort4 r0, r1;
    r0.x = f2bf(a.x); r0.y = f2bf(a.y); r0.z = f2bf(a.z); r0.w = f2bf(a.w);
    r1.x = f2bf(b.x); r1.y = f2bf(b.y); r1.z = f2bf(b.z); r1.w = f2bf(b.w);
    *(ushort4*)&dst[off] = r0;
    *(ushort4*)&dst[off + 4] = r1;
}

// ---------------------------------------------------------------------------
// fp32 W[R][C] -> bf16 W^T[C][R], 64x64 LDS tiles. grid (C/64, R/64).
// ---------------------------------------------------------------------------
__global__ __launch_bounds__(256) void cvt_w_t(const float* __restrict__ src,
                                               u16* __restrict__ dst, int R, int C)
{
    __shared__ u16 t[64][72];
    const int r0 = blockIdx.y * 64, c0 = blockIdx.x * 64;
    const int tid = threadIdx.x;
    const int tr = tid >> 4, tc4 = (tid & 15) * 4;
#pragma unroll
    for (int p = 0; p < 4; p++) {
        int r = p * 16 + tr;
        float4 v = *(const float4*)&src[(size_t)(r0 + r) * C + c0 + tc4];
        t[tc4 + 0][r] = f2bf(v.x);
        t[tc4 + 1][r] = f2bf(v.y);
        t[tc4 + 2][r] = f2bf(v.z);
        t[tc4 + 3][r] = f2bf(v.w);
    }
    __syncthreads();
#pragma unroll
    for (int p = 0; p < 4; p++) {
        int cc = p * 16 + tr;
        ushort4 w = *(const ushort4*)&t[cc][tc4];
        *(ushort4*)&dst[(size_t)(c0 + cc) * R + r0 + tc4] = w;
    }
}

// ---------------------------------------------------------------------------
// bf16 MFMA GEMM mainloop (m97 structure): C128x128 = A[m0:,K] @ Bt[n0:,K]^T.
// 256 thr / 4 waves in 2x2; BK=32; global_load_lds 16B staging; acc 4x4 of
// 16x16x32 MFMA per wave.
// ---------------------------------------------------------------------------
__device__ __forceinline__ void bf16_gemm_mainloop(const u16* __restrict__ A,
                                                   const u16* __restrict__ Bt,
                                                   int m0, int n0,
                                                   u16 (&As)[128 * 32],
                                                   u16 (&Bs)[128 * 32],
                                                   f32x4 (&acc)[4][4])
{
    const int tid = threadIdx.x;
    const int wv = tid >> 6, lane = tid & 63;
    const int l15 = lane & 15, quad = lane >> 4;
    const int wr = wv >> 1, wc = wv & 1;

#pragma unroll
    for (int mt = 0; mt < 4; mt++)
#pragma unroll
        for (int nt = 0; nt < 4; nt++) acc[mt][nt] = (f32x4){0.f, 0.f, 0.f, 0.f};

    for (int k0 = 0; k0 < 2048; k0 += 32) {
        __syncthreads();   // previous iter's ds_reads complete before overwrite
#pragma unroll
        for (int j = 0; j < 2; j++) {
            int c = wv * 128 + j * 64 + lane;         // chunk id 0..511
            const u16* ga = A + (size_t)(m0 + (c >> 2)) * 2048 + k0 + (c & 3) * 8;
            gload16(ga, &As[(wv * 128 + j * 64) * 8]);
            const u16* gb = Bt + (size_t)(n0 + (c >> 2)) * 2048 + k0 + (c & 3) * 8;
            gload16(gb, &Bs[(wv * 128 + j * 64) * 8]);
        }
        __syncthreads();   // staging visible (compiler emits vmcnt drain)

        bf16x8 af[4], bfr[4];
#pragma unroll
        for (int mt = 0; mt < 4; mt++)
            af[mt] = *(const bf16x8*)&As[(wr * 64 + mt * 16 + l15) * 32 + quad * 8];
#pragma unroll
        for (int nt = 0; nt < 4; nt++)
            bfr[nt] = *(const bf16x8*)&Bs[(wc * 64 + nt * 16 + l15) * 32 + quad * 8];
#pragma unroll
        for (int mt = 0; mt < 4; mt++)
#pragma unroll
            for (int nt = 0; nt < 4; nt++)
                acc[mt][nt] = __builtin_amdgcn_mfma_f32_16x16x32_bf16(af[mt], bfr[nt], acc[mt][nt], 0, 0, 0);
    }
}

// Fused QKV: grid (24, 32). x<16: Q -> qraw bf16[4096][2048]; x in [16,20): K ->
// kraw bf16[4096][512]; x >= 20: V -> vt bf16 transposed [(b*4+kvh)*128+h][2048].
__global__ __launch_bounds__(256) void qkv_gemm_bf(const u16* __restrict__ Xq,
                                                   const u16* __restrict__ Xkv,
                                                   const u16* __restrict__ Wqt,
                                                   const u16* __restrict__ Wkt,
                                                   const u16* __restrict__ Wvt,
                                                   u16* __restrict__ qraw,
                                                   u16* __restrict__ kraw,
                                                   u16* __restrict__ vt)
{
    __shared__ __align__(16) u16 As[128 * 32];
    __shared__ __align__(16) u16 Bs[128 * 32];
    f32x4 acc[4][4];
    const int bx = blockIdx.x, m0 = blockIdx.y * 128;
    const u16 *A, *Bt; int n0;
    if (bx < 16)      { A = Xq;  Bt = Wqt; n0 = bx * 128; }
    else if (bx < 20) { A = Xkv; Bt = Wkt; n0 = (bx - 16) * 128; }
    else              { A = Xkv; Bt = Wvt; n0 = (bx - 20) * 128; }
    bf16_gemm_mainloop(A, Bt, m0, n0, As, Bs, acc);

    const int tid = threadIdx.x;
    const int wv = tid >> 6, lane = tid & 63;
    const int l15 = lane & 15, quad = lane >> 4;
    const int wr = wv >> 1, wc = wv & 1;

    if (bx < 20) {
        u16* out; int ldw;
        if (bx < 16) { out = qraw; ldw = 2048; }
        else         { out = kraw; ldw = 512; }
#pragma unroll
        for (int mt = 0; mt < 4; mt++)
#pragma unroll
            for (int nt = 0; nt < 4; nt++) {
                int col = n0 + wc * 64 + nt * 16 + l15;
                int r = m0 + wr * 64 + mt * 16 + quad * 4;
#pragma unroll
                for (int reg = 0; reg < 4; reg++)
                    out[(size_t)(r + reg) * ldw + col] = f2bf(acc[mt][nt][reg]);
            }
    } else {
        const int b = m0 >> 11, tb = m0 & 2047;
#pragma unroll
        for (int mt = 0; mt < 4; mt++)
#pragma unroll
            for (int nt = 0; nt < 4; nt++) {
                int col = n0 + wc * 64 + nt * 16 + l15;       // kvh*128 + h, 0..511
                int tloc = tb + wr * 64 + mt * 16 + quad * 4;
                ushort4 w4;
                w4.x = f2bf(acc[mt][nt][0]);
                w4.y = f2bf(acc[mt][nt][1]);
                w4.z = f2bf(acc[mt][nt][2]);
                w4.w = f2bf(acc[mt][nt][3]);
                *(ushort4*)&vt[((size_t)b * 512 + col) * 2048 + tloc] = w4;
            }
    }
}

// Output projection: grid (16, 32). out fp32 = attn_bf[4096][2048] @ Wo_t^T.
__global__ __launch_bounds__(256) void oproj_gemm_bf(const u16* __restrict__ attnb,
                                                     const u16* __restrict__ Wot,
                                                     float* __restrict__ out)
{
    __shared__ __align__(16) u16 As[128 * 32];
    __shared__ __align__(16) u16 Bs[128 * 32];
    f32x4 acc[4][4];
    const int m0 = blockIdx.y * 128, n0 = blockIdx.x * 128;
    bf16_gemm_mainloop(attnb, Wot, m0, n0, As, Bs, acc);
    const int tid = threadIdx.x;
    const int wv = tid >> 6, lane = tid & 63;
    const int l15 = lane & 15, quad = lane >> 4;
    const int wr = wv >> 1, wc = wv & 1;
#pragma unroll
    for (int mt = 0; mt < 4; mt++)
#pragma unroll
        for (int nt = 0; nt < 4; nt++) {
            int col = n0 + wc * 64 + nt * 16 + l15;
            int r = m0 + wr * 64 + mt * 16 + quad * 4;
#pragma unroll
            for (int reg = 0; reg < 4; reg++)
                out[(size_t)(r + reg) * 2048 + col] = acc[mt][nt][reg];
        }
}

// In-place RoPE on bf16 q/k. 4 (h,h+64) pairs per thread.
__global__ __launch_bounds__(256) void rope_bf(u16* __restrict__ q,
                                               u16* __restrict__ k,
                                               const int* __restrict__ qpos,
                                               const int* __restrict__ kvpos)
{
    const int qTh = Bdim * Tdim * NHq * 16;   // 1,048,576
    int idx = blockIdx.x * 256 + threadIdx.x;
    u16* base; int h4; int pos;
    if (idx < qTh) {
        int rn = idx >> 4; h4 = (idx & 15) * 4;
        pos = qpos[rn >> 4];
        base = q + (size_t)rn * HD;
    } else {
        int j = idx - qTh;
        int rn = j >> 4; h4 = (j & 15) * 4;
        pos = kvpos[rn >> 2];
        base = k + (size_t)rn * HD;
    }
    ushort4 a = *(const ushort4*)&base[h4];
    ushort4 bvec = *(const ushort4*)&base[h4 + 64];
    u16 av[4] = {a.x, a.y, a.z, a.w};
    u16 bv[4] = {bvec.x, bvec.y, bvec.z, bvec.w};
#pragma unroll
    for (int j = 0; j < 4; j++) {
        float inv_ts = expf(-(float)(h4 + j) * 0.14391156831f);  // 10000^(-h/64)
        float ang = (float)pos * inv_ts;
        float s, c;
        sincosf(ang, &s, &c);
        float x1 = bf2f(av[j]), x2 = bf2f(bv[j]);
        av[j] = f2bf(x1 * c - x2 * s);
        bv[j] = f2bf(x2 * c + x1 * s);
    }
    ushort4 ra, rb;
    ra.x = av[0]; ra.y = av[1]; ra.z = av[2]; ra.w = av[3];
    rb.x = bv[0]; rb.y = bv[1]; rb.z = bv[2]; rb.w = bv[3];
    *(ushort4*)&base[h4] = ra;
    *(ushort4*)&base[h4 + 64] = rb;
}

// ---------------------------------------------------------------------------
// MFMA flash attention (unchanged from R2 except bf16 output).
// ---------------------------------------------------------------------------
__global__ __launch_bounds__(256) void flash_attn_mfma(const u16* __restrict__ qh,
                                                       const u16* __restrict__ kh,
                                                       const u16* __restrict__ vt,
                                                       u16* __restrict__ attn)
{
    __shared__ __align__(16) u16 Ks[64 * 128];
    __shared__ __align__(16) u16 Vt[128 * 64];
    __shared__ __align__(16) u16 QP[64 * 128];

    const int qt = 31 - (int)blockIdx.x;
    const int bh = blockIdx.y;
    const int b = bh >> 4, n = bh & 15, kvh = n >> 2;
    const int q0 = qt * 64;
    const int tid = threadIdx.x;
    const int wv = tid >> 6;
    const int lane = tid & 63;
    const int l15 = lane & 15, quad = lane >> 4;

    {
        const size_t qbase = (((size_t)(b * Tdim + q0)) * NHq + n) * HD;
        const int mrow_ = tid >> 4, c8 = tid & 15;
#pragma unroll
        for (int p = 0; p < 4; p++) {
            int m = p * 16 + mrow_;
            bf16x8 qv = *(const bf16x8*)(qh + qbase + (size_t)m * (NHq * HD) + c8 * 8);
            int cb = c8 ^ (m & 7);
            *(bf16x8*)&QP[m * 128 + cb * 8] = qv;
        }
    }
    __syncthreads();

    bf16x8 qfrag[4];
    {
        int m = wv * 16 + l15;
#pragma unroll
        for (int kt = 0; kt < 4; kt++) {
            int cb = (kt * 4 + quad) ^ (m & 7);
            qfrag[kt] = *(const bf16x8*)&QP[m * 128 + cb * 8];
        }
    }

    f32x4 Oacc[8];
#pragma unroll
    for (int ht = 0; ht < 8; ht++) Oacc[ht] = (f32x4){0.f, 0.f, 0.f, 0.f};
    float mrow[4] = {NEG_INF, NEG_INF, NEG_INF, NEG_INF};
    float lrow[4] = {0.f, 0.f, 0.f, 0.f};

    const size_t kbase = (((size_t)(b * Tdim)) * NKV + kvh) * HD;
    const size_t vbase = ((size_t)(b * NKV + kvh)) * HD * Tdim;

    for (int t = 0; t <= qt; t++) {
        const int s0 = t * 64;
        __syncthreads();
        {
            const int r16 = tid >> 4, c8 = tid & 15;
#pragma unroll
            for (int p = 0; p < 4; p++) {
                int s = p * 16 + r16;
                bf16x8 kv = *(const bf16x8*)(kh + kbase + (size_t)(s0 + s) * (NKV * HD) + c8 * 8);
                int cb = c8 ^ (s & 7);
                *(bf16x8*)&Ks[s * 128 + cb * 8] = kv;
            }
            const int h8 = tid >> 3, sb = tid & 7;
#pragma unroll
            for (int p = 0; p < 4; p++) {
                int h = p * 32 + h8;
                bf16x8 vv = *(const bf16x8*)(vt + vbase + (size_t)h * Tdim + s0 + sb * 8);
                int cb = sb ^ (h & 7);
                *(bf16x8*)&Vt[h * 64 + cb * 8] = vv;
            }
        }
        __syncthreads();

        f32x4 S[4];
#pragma unroll
        for (int nt = 0; nt < 4; nt++) S[nt] = (f32x4){0.f, 0.f, 0.f, 0.f};
#pragma unroll
        for (int kt = 0; kt < 4; kt++) {
#pragma unroll
            for (int nt = 0; nt < 4; nt++) {
                int sl = nt * 16 + l15;
                int cb = (kt * 4 + quad) ^ (l15 & 7);
                bf16x8 bfrg = *(const bf16x8*)&Ks[sl * 128 + cb * 8];
                S[nt] = __builtin_amdgcn_mfma_f32_16x16x32_bf16(qfrag[kt], bfrg, S[nt], 0, 0, 0);
            }
        }

        const bool masked = (t == qt);
#pragma unroll
        for (int r = 0; r < 4; r++) {
            const int ml = wv * 16 + quad * 4 + r;
            float sv[4];
            float mx = NEG_INF;
#pragma unroll
            for (int nt = 0; nt < 4; nt++) {
                float vvv = S[nt][r] * SCALE;
                if (masked && (nt * 16 + l15 > ml)) vvv = NEG_INF;
                sv[nt] = vvv;
                mx = fmaxf(mx, vvv);
            }
            mx = fmaxf(mx, __shfl_xor(mx, 1));
            mx = fmaxf(mx, __shfl_xor(mx, 2));
            mx = fmaxf(mx, __shfl_xor(mx, 4));
            mx = fmaxf(mx, __shfl_xor(mx, 8));
            float mNew = fmaxf(mrow[r], mx);
            float alpha = __expf(mrow[r] - mNew);
            mrow[r] = mNew;
            float ps = 0.f;
#pragma unroll
            for (int nt = 0; nt < 4; nt++) {
                float p = __expf(sv[nt] - mNew);
                sv[nt] = p;
                ps += p;
            }
            ps += __shfl_xor(ps, 1);
            ps += __shfl_xor(ps, 2);
            ps += __shfl_xor(ps, 4);
            ps += __shfl_xor(ps, 8);
            lrow[r] = lrow[r] * alpha + ps;
#pragma unroll
            for (int ht = 0; ht < 8; ht++) Oacc[ht][r] *= alpha;
            const int m = ml;
#pragma unroll
            for (int nt = 0; nt < 4; nt++) {
                int s = nt * 16 + l15;
                int cb = (s >> 3) ^ (m & 7);
                QP[m * 64 + cb * 8 + (s & 7)] = f2bf(sv[nt]);
            }
        }

        bf16x8 pfrag[2];
        {
            int m = wv * 16 + l15;
#pragma unroll
            for (int k2 = 0; k2 < 2; k2++) {
                int cb = (k2 * 4 + quad) ^ (m & 7);
                pfrag[k2] = *(const bf16x8*)&QP[m * 64 + cb * 8];
            }
        }

#pragma unroll
        for (int k2 = 0; k2 < 2; k2++) {
#pragma unroll
            for (int ht = 0; ht < 8; ht++) {
                int h = ht * 16 + l15;
                int cb = (k2 * 4 + quad) ^ (l15 & 7);
                bf16x8 vfrg = *(const bf16x8*)&Vt[h * 64 + cb * 8];
                Oacc[ht] = __builtin_amdgcn_mfma_f32_16x16x32_bf16(pfrag[k2], vfrg, Oacc[ht], 0, 0, 0);
            }
        }
    }

#pragma unroll
    for (int r = 0; r < 4; r++) {
        float inv = 1.0f / lrow[r];
        int mg = q0 + wv * 16 + quad * 4 + r;
        u16* dst = attn + (((size_t)(b * Tdim + mg)) * NHq + n) * HD + l15;
#pragma unroll
        for (int ht = 0; ht < 8; ht++) {
            dst[ht * 16] = f2bf(Oacc[ht][r] * inv);
        }
    }
}

extern "C" void kernel_launch(void* const* d_in, const int* in_sizes, int n_in,
                              void* d_out, int out_size, void* d_ws, size_t ws_size,
                              hipStream_t stream) {
    const float* Xq    = (const float*)d_in[0];
    const float* Xkv   = (const float*)d_in[1];
    const int*   qpos  = (const int*)d_in[2];
    const int*   kvpos = (const int*)d_in[3];
    const float* Wq    = (const float*)d_in[4];
    const float* Wk    = (const float*)d_in[5];
    const float* Wv    = (const float*)d_in[6];
    const float* Wo    = (const float*)d_in[7];
    float* out = (float*)d_out;

    char* w = (char*)d_ws;
    u16* xq_bf = (u16*)(w);                    // 16 MB [4096][2048]
    u16* xkv_bf= (u16*)(w + (16u << 20));      // 16 MB [4096][2048]
    u16* qraw  = (u16*)(w + (32u << 20));      // 16 MB [4096][2048] (roped in place)
    u16* kraw  = (u16*)(w + (48u << 20));      //  4 MB [4096][512]  (roped in place)
    u16* vt    = (u16*)(w + (52u << 20));      //  4 MB [(b*4+kvh)*128+h][2048]
    u16* wq_t  = (u16*)(w + (56u << 20));      //  8 MB [2048][2048]
    u16* wk_t  = (u16*)(w + (64u << 20));      //  2 MB [512][2048]
    u16* wv_t  = (u16*)(w + (66u << 20));      //  2 MB [512][2048]
    u16* wo_t  = (u16*)(w + (68u << 20));      //  8 MB [2048][2048]
    u16* attnb = (u16*)(w);                    // 16 MB, aliases xq_bf (dead by then)

    cvt_x<<<8192, 256, 0, stream>>>(Xq, Xkv, xq_bf, xkv_bf);
    cvt_w_t<<<dim3(32, 32), 256, 0, stream>>>(Wq, wq_t, 2048, 2048);
    cvt_w_t<<<dim3(8, 32),  256, 0, stream>>>(Wk, wk_t, 2048, 512);
    cvt_w_t<<<dim3(8, 32),  256, 0, stream>>>(Wv, wv_t, 2048, 512);
    cvt_w_t<<<dim3(32, 32), 256, 0, stream>>>(Wo, wo_t, 2048, 2048);
    qkv_gemm_bf<<<dim3(24, 32), 256, 0, stream>>>(xq_bf, xkv_bf, wq_t, wk_t, wv_t,
                                                  qraw, kraw, vt);
    rope_bf<<<5120, 256, 0, stream>>>(qraw, kraw, qpos, kvpos);
    flash_attn_mfma<<<dim3(32, 32), 256, 0, stream>>>(qraw, kraw, vt, attnb);
    oproj_gemm_bf<<<dim3(16, 32), 256, 0, stream>>>(attnb, wo_t, out);
}

// Round 4
// 407.513 us; speedup vs baseline: 5.9369x; 1.1876x over previous
//
#include <hip/hip_runtime.h>
#include <hip/hip_bf16.h>
#include <cstdint>
#include <cstddef>

#define Bdim 2
#define Tdim 2048
#define Ddim 2048
#define NHq  16
#define NKV  4
#define HD   128
#define SCALE 0.08838834764831845f
#define NEG_INF (-3.0e38f)

typedef unsigned short u16;
typedef unsigned int   u32;
typedef __bf16 bf16x8 __attribute__((ext_vector_type(8)));
typedef float  f32x4  __attribute__((ext_vector_type(4)));

__device__ __forceinline__ u16 f2bf(float f) {
    unsigned int u = __float_as_uint(f);
    u += 0x7FFFu + ((u >> 16) & 1u);   // RNE
    return (u16)(u >> 16);
}
__device__ __forceinline__ float bf2f(u16 s) {
    return __uint_as_float(((unsigned int)s) << 16);
}

// async global->LDS, 16B per lane. LDS dest is wave-uniform base + lane*16.
typedef __attribute__((address_space(1))) const u32 gbl_u32;
typedef __attribute__((address_space(3))) u32 lds_u32;
__device__ __forceinline__ void gload16(const void* g, void* l) {
    __builtin_amdgcn_global_load_lds((gbl_u32*)(uintptr_t)g, (lds_u32*)(uintptr_t)l, 16, 0, 0);
}

// ---------------------------------------------------------------------------
// fp32 -> bf16 straight convert for Xq, Xkv. 8 elems/thread.
// ---------------------------------------------------------------------------
__global__ __launch_bounds__(256) void cvt_x(const float* __restrict__ Xq,
                                             const float* __restrict__ Xkv,
                                             u16* __restrict__ oq,
                                             u16* __restrict__ okv)
{
    const size_t NE = (size_t)4096 * 2048 / 8;
    size_t idx = (size_t)blockIdx.x * 256 + threadIdx.x;
    const float* src; u16* dst; size_t off;
    if (idx < NE) { src = Xq;  dst = oq;  off = idx * 8; }
    else          { src = Xkv; dst = okv; off = (idx - NE) * 8; }
    float4 a = *(const float4*)&src[off];
    float4 b = *(const float4*)&src[off + 4];
    ushort4 r0, r1;
    r0.x = f2bf(a.x); r0.y = f2bf(a.y); r0.z = f2bf(a.z); r0.w = f2bf(a.w);
    r1.x = f2bf(b.x); r1.y = f2bf(b.y); r1.z = f2bf(b.z); r1.w = f2bf(b.w);
    *(ushort4*)&dst[off] = r0;
    *(ushort4*)&dst[off + 4] = r1;
}

// ---------------------------------------------------------------------------
// fp32 W[R][C] -> bf16 W^T[C][R], 64x64 LDS tiles. grid (C/64, R/64).
// ---------------------------------------------------------------------------
__global__ __launch_bounds__(256) void cvt_w_t(const float* __restrict__ src,
                                               u16* __restrict__ dst, int R, int C)
{
    __shared__ u16 t[64][72];
    const int r0 = blockIdx.y * 64, c0 = blockIdx.x * 64;
    const int tid = threadIdx.x;
    const int tr = tid >> 4, tc4 = (tid & 15) * 4;
#pragma unroll
    for (int p = 0; p < 4; p++) {
        int r = p * 16 + tr;
        float4 v = *(const float4*)&src[(size_t)(r0 + r) * C + c0 + tc4];
        t[tc4 + 0][r] = f2bf(v.x);
        t[tc4 + 1][r] = f2bf(v.y);
        t[tc4 + 2][r] = f2bf(v.z);
        t[tc4 + 3][r] = f2bf(v.w);
    }
    __syncthreads();
#pragma unroll
    for (int p = 0; p < 4; p++) {
        int cc = p * 16 + tr;
        ushort4 w = *(const ushort4*)&t[cc][tc4];
        *(ushort4*)&dst[(size_t)(c0 + cc) * R + r0 + tc4] = w;
    }
}

// ---------------------------------------------------------------------------
// bf16 MFMA GEMM mainloop (m97 structure)
// ---------------------------------------------------------------------------
__device__ __forceinline__ void bf16_gemm_mainloop(const u16* __restrict__ A,
                                                   const u16* __restrict__ Bt,
                                                   int m0, int n0,
                                                   u16 (&As)[128 * 32],
                                                   u16 (&Bs)[128 * 32],
                                                   f32x4 (&acc)[4][4])
{
    const int tid = threadIdx.x;
    const int wv = tid >> 6, lane = tid & 63;
    const int l15 = lane & 15, quad = lane >> 4;
    const int wr = wv >> 1, wc = wv & 1;

#pragma unroll
    for (int mt = 0; mt < 4; mt++)
#pragma unroll
        for (int nt = 0; nt < 4; nt++) acc[mt][nt] = (f32x4){0.f, 0.f, 0.f, 0.f};

    for (int k0 = 0; k0 < 2048; k0 += 32) {
        __syncthreads();
#pragma unroll
        for (int j = 0; j < 2; j++) {
            int c = wv * 128 + j * 64 + lane;
            const u16* ga = A + (size_t)(m0 + (c >> 2)) * 2048 + k0 + (c & 3) * 8;
            gload16(ga, &As[(wv * 128 + j * 64) * 8]);
            const u16* gb = Bt + (size_t)(n0 + (c >> 2)) * 2048 + k0 + (c & 3) * 8;
            gload16(gb, &Bs[(wv * 128 + j * 64) * 8]);
        }
        __syncthreads();

        bf16x8 af[4], bfr[4];
#pragma unroll
        for (int mt = 0; mt < 4; mt++)
            af[mt] = *(const bf16x8*)&As[(wr * 64 + mt * 16 + l15) * 32 + quad * 8];
#pragma unroll
        for (int nt = 0; nt < 4; nt++)
            bfr[nt] = *(const bf16x8*)&Bs[(wc * 64 + nt * 16 + l15) * 32 + quad * 8];
#pragma unroll
        for (int mt = 0; mt < 4; mt++)
#pragma unroll
            for (int nt = 0; nt < 4; nt++)
                acc[mt][nt] = __builtin_amdgcn_mfma_f32_16x16x32_bf16(af[mt], bfr[nt], acc[mt][nt], 0, 0, 0);
    }
}

// Fused QKV: grid (24, 32).
__global__ __launch_bounds__(256) void qkv_gemm_bf(const u16* __restrict__ Xq,
                                                   const u16* __restrict__ Xkv,
                                                   const u16* __restrict__ Wqt,
                                                   const u16* __restrict__ Wkt,
                                                   const u16* __restrict__ Wvt,
                                                   u16* __restrict__ qraw,
                                                   u16* __restrict__ kraw,
                                                   u16* __restrict__ vt)
{
    __shared__ __align__(16) u16 As[128 * 32];
    __shared__ __align__(16) u16 Bs[128 * 32];
    f32x4 acc[4][4];
    const int bx = blockIdx.x, m0 = blockIdx.y * 128;
    const u16 *A, *Bt; int n0;
    if (bx < 16)      { A = Xq;  Bt = Wqt; n0 = bx * 128; }
    else if (bx < 20) { A = Xkv; Bt = Wkt; n0 = (bx - 16) * 128; }
    else              { A = Xkv; Bt = Wvt; n0 = (bx - 20) * 128; }
    bf16_gemm_mainloop(A, Bt, m0, n0, As, Bs, acc);

    const int tid = threadIdx.x;
    const int wv = tid >> 6, lane = tid & 63;
    const int l15 = lane & 15, quad = lane >> 4;
    const int wr = wv >> 1, wc = wv & 1;

    if (bx < 20) {
        u16* out; int ldw;
        if (bx < 16) { out = qraw; ldw = 2048; }
        else         { out = kraw; ldw = 512; }
#pragma unroll
        for (int mt = 0; mt < 4; mt++)
#pragma unroll
            for (int nt = 0; nt < 4; nt++) {
                int col = n0 + wc * 64 + nt * 16 + l15;
                int r = m0 + wr * 64 + mt * 16 + quad * 4;
#pragma unroll
                for (int reg = 0; reg < 4; reg++)
                    out[(size_t)(r + reg) * ldw + col] = f2bf(acc[mt][nt][reg]);
            }
    } else {
        const int b = m0 >> 11, tb = m0 & 2047;
#pragma unroll
        for (int mt = 0; mt < 4; mt++)
#pragma unroll
            for (int nt = 0; nt < 4; nt++) {
                int col = n0 + wc * 64 + nt * 16 + l15;
                int tloc = tb + wr * 64 + mt * 16 + quad * 4;
                ushort4 w4;
                w4.x = f2bf(acc[mt][nt][0]);
                w4.y = f2bf(acc[mt][nt][1]);
                w4.z = f2bf(acc[mt][nt][2]);
                w4.w = f2bf(acc[mt][nt][3]);
                *(ushort4*)&vt[((size_t)b * 512 + col) * 2048 + tloc] = w4;
            }
    }
}

// Output projection: grid (16, 32).
__global__ __launch_bounds__(256) void oproj_gemm_bf(const u16* __restrict__ attnb,
                                                     const u16* __restrict__ Wot,
                                                     float* __restrict__ out)
{
    __shared__ __align__(16) u16 As[128 * 32];
    __shared__ __align__(16) u16 Bs[128 * 32];
    f32x4 acc[4][4];
    const int m0 = blockIdx.y * 128, n0 = blockIdx.x * 128;
    bf16_gemm_mainloop(attnb, Wot, m0, n0, As, Bs, acc);
    const int tid = threadIdx.x;
    const int wv = tid >> 6, lane = tid & 63;
    const int l15 = lane & 15, quad = lane >> 4;
    const int wr = wv >> 1, wc = wv & 1;
#pragma unroll
    for (int mt = 0; mt < 4; mt++)
#pragma unroll
        for (int nt = 0; nt < 4; nt++) {
            int col = n0 + wc * 64 + nt * 16 + l15;
            int r = m0 + wr * 64 + mt * 16 + quad * 4;
#pragma unroll
            for (int reg = 0; reg < 4; reg++)
                out[(size_t)(r + reg) * 2048 + col] = acc[mt][nt][reg];
        }
}

// In-place RoPE on bf16 q/k.
__global__ __launch_bounds__(256) void rope_bf(u16* __restrict__ q,
                                               u16* __restrict__ k,
                                               const int* __restrict__ qpos,
                                               const int* __restrict__ kvpos)
{
    const int qTh = Bdim * Tdim * NHq * 16;
    int idx = blockIdx.x * 256 + threadIdx.x;
    u16* base; int h4; int pos;
    if (idx < qTh) {
        int rn = idx >> 4; h4 = (idx & 15) * 4;
        pos = qpos[rn >> 4];
        base = q + (size_t)rn * HD;
    } else {
        int j = idx - qTh;
        int rn = j >> 4; h4 = (j & 15) * 4;
        pos = kvpos[rn >> 2];
        base = k + (size_t)rn * HD;
    }
    ushort4 a = *(const ushort4*)&base[h4];
    ushort4 bvec = *(const ushort4*)&base[h4 + 64];
    u16 av[4] = {a.x, a.y, a.z, a.w};
    u16 bv[4] = {bvec.x, bvec.y, bvec.z, bvec.w};
#pragma unroll
    for (int j = 0; j < 4; j++) {
        float inv_ts = expf(-(float)(h4 + j) * 0.14391156831f);
        float ang = (float)pos * inv_ts;
        float s, c;
        sincosf(ang, &s, &c);
        float x1 = bf2f(av[j]), x2 = bf2f(bv[j]);
        av[j] = f2bf(x1 * c - x2 * s);
        bv[j] = f2bf(x2 * c + x1 * s);
    }
    ushort4 ra, rb;
    ra.x = av[0]; ra.y = av[1]; ra.z = av[2]; ra.w = av[3];
    rb.x = bv[0]; rb.y = bv[1]; rb.z = bv[2]; rb.w = bv[3];
    *(ushort4*)&base[h4] = ra;
    *(ushort4*)&base[h4 + 64] = rb;
}

// ---------------------------------------------------------------------------
// Flash attention v2: BQ=128 (4 waves x 32 rows), BKV=64, transposed-S.
// Grid (32 bh, 16 qt reversed). global_load_lds staging w/ XOR-swizzled source.
// ---------------------------------------------------------------------------
__global__ __launch_bounds__(256) void flash_attn_v2(const u16* __restrict__ qh,
                                                     const u16* __restrict__ kh,
                                                     const u16* __restrict__ vtg,
                                                     u16* __restrict__ attnb)
{
    // Ks[s][h]: chunk cb = c8 ^ (s&7); addr = s*128 + cb*8 + (h&7)
    __shared__ __align__(16) u16 Ks[64 * 128];
    // Vt[h][s]: chunk cb = sb ^ (h&7); addr = h*64 + cb*8 + (s&7)
    __shared__ __align__(16) u16 Vt[128 * 64];
    // Ps[m][s]: chunk cb = sb ^ (m&7)
    __shared__ __align__(16) u16 Ps[128 * 64];
    __shared__ float aArr[4][2][16];
    __shared__ float lArr[4][2][16];

    const int qt = 15 - (int)blockIdx.y;   // longest first
    const int bh = blockIdx.x;
    const int b = bh >> 4, n = bh & 15, kvh = n >> 2;
    const int q0 = qt * 128;
    const int tid = threadIdx.x;
    const int wv = tid >> 6, lane = tid & 63;
    const int l15 = lane & 15, quad = lane >> 4;

    // ---- Q fragments direct from global (B-operand: n=l15->m, k=quad*8+j->h) ----
    bf16x8 qfrag[2][4];
    {
        const size_t qbase = ((size_t)(b * Tdim + q0 + wv * 32)) * 2048 + n * 128;
#pragma unroll
        for (int mt = 0; mt < 2; mt++)
#pragma unroll
            for (int kt = 0; kt < 4; kt++)
                qfrag[mt][kt] = *(const bf16x8*)(qh + qbase + (size_t)(mt * 16 + l15) * 2048
                                                 + kt * 32 + quad * 8);
    }

    f32x4 Oacc[2][8];
#pragma unroll
    for (int mt = 0; mt < 2; mt++)
#pragma unroll
        for (int ht = 0; ht < 8; ht++) Oacc[mt][ht] = (f32x4){0.f, 0.f, 0.f, 0.f};
    float mrow[2] = {NEG_INF, NEG_INF};
    float lrow[2] = {0.f, 0.f};

    const size_t kbase = (size_t)(b * Tdim) * 512 + kvh * 128;
    const size_t vbase = ((size_t)(b * 512 + kvh * 128)) * 2048;
    const int nT = 2 * qt + 2;

    for (int t = 0; t < nT; t++) {
        const int s0 = t * 64;
        __syncthreads();   // prev iter's frag reads done before overwrite
        // ---- stage K (16KB) and V (16KB) via global_load_lds, swizzled source ----
#pragma unroll
        for (int c = 0; c < 4; c++) {
            int j = c * 256 + tid;
            int s = j >> 4;
            int c8 = (j & 15) ^ (s & 7);
            gload16(kh + kbase + (size_t)(s0 + s) * 512 + c8 * 8,
                    &Ks[(c * 256 + wv * 64) * 8]);
            int h = j >> 3;
            int sb = (j & 7) ^ (h & 7);
            gload16(vtg + vbase + (size_t)h * 2048 + s0 + sb * 8,
                    &Vt[(c * 256 + wv * 64) * 8]);
        }
        __syncthreads();   // vmcnt drain before reads

        // ---- S^T = K Q^T : tiles nt (s) x mt (m) ----
        f32x4 S[2][4];
#pragma unroll
        for (int mt = 0; mt < 2; mt++)
#pragma unroll
            for (int nt = 0; nt < 4; nt++) S[mt][nt] = (f32x4){0.f, 0.f, 0.f, 0.f};
#pragma unroll
        for (int kt = 0; kt < 4; kt++) {
            bf16x8 kf[4];
#pragma unroll
            for (int nt = 0; nt < 4; nt++) {
                int s = nt * 16 + l15;
                int cb = (kt * 4 + quad) ^ (s & 7);
                kf[nt] = *(const bf16x8*)&Ks[s * 128 + cb * 8];
            }
#pragma unroll
            for (int mt = 0; mt < 2; mt++)
#pragma unroll
                for (int nt = 0; nt < 4; nt++)
                    S[mt][nt] = __builtin_amdgcn_mfma_f32_16x16x32_bf16(kf[nt], qfrag[mt][kt], S[mt][nt], 0, 0, 0);
        }

        // ---- online softmax in S^T domain (lane owns one m per mt) ----
        const bool domask = (t >= nT - 2);
#pragma unroll
        for (int mt = 0; mt < 2; mt++) {
            const int m_l = wv * 32 + mt * 16 + l15;
            const int mg = q0 + m_l;
            float sv[16];
            float mx = NEG_INF;
#pragma unroll
            for (int nt = 0; nt < 4; nt++)
#pragma unroll
                for (int r = 0; r < 4; r++) {
                    float vv = S[mt][nt][r] * SCALE;
                    if (domask) {
                        int sg = s0 + nt * 16 + quad * 4 + r;
                        if (sg > mg) vv = NEG_INF;
                    }
                    sv[nt * 4 + r] = vv;
                    mx = fmaxf(mx, vv);
                }
            mx = fmaxf(mx, __shfl_xor(mx, 16));
            mx = fmaxf(mx, __shfl_xor(mx, 32));
            float mNew = fmaxf(mrow[mt], mx);   // always finite (s=0..m real)
            float alpha = __expf(mrow[mt] - mNew);
            mrow[mt] = mNew;
            float ps = 0.f;
#pragma unroll
            for (int i = 0; i < 16; i++) {
                float p = __expf(sv[i] - mNew);  // masked -> exp(-3e38-m) = 0
                sv[i] = p;
                ps += p;
            }
            ps += __shfl_xor(ps, 16);
            ps += __shfl_xor(ps, 32);
            lrow[mt] = lrow[mt] * alpha + ps;
            if (quad == 0) aArr[wv][mt][l15] = alpha;
            // P write: per nt, 4 contiguous s -> ds_write_b64
#pragma unroll
            for (int nt = 0; nt < 4; nt++) {
                int sb = nt * 2 + (quad >> 1);
                int cb = sb ^ (m_l & 7);
                ushort4 pw;
                pw.x = f2bf(sv[nt * 4 + 0]);
                pw.y = f2bf(sv[nt * 4 + 1]);
                pw.z = f2bf(sv[nt * 4 + 2]);
                pw.w = f2bf(sv[nt * 4 + 3]);
                *(ushort4*)&Ps[m_l * 64 + cb * 8 + (quad & 1) * 4] = pw;
            }
        }

        // ---- rescale O by alpha (broadcast via LDS, same-wave ordering) ----
#pragma unroll
        for (int mt = 0; mt < 2; mt++) {
            f32x4 al4 = *(const f32x4*)&aArr[wv][mt][quad * 4];
#pragma unroll
            for (int ht = 0; ht < 8; ht++) {
                Oacc[mt][ht][0] *= al4[0];
                Oacc[mt][ht][1] *= al4[1];
                Oacc[mt][ht][2] *= al4[2];
                Oacc[mt][ht][3] *= al4[3];
            }
        }

        // ---- O += P V ----
#pragma unroll
        for (int k2 = 0; k2 < 2; k2++) {
            bf16x8 pf[2];
#pragma unroll
            for (int mt = 0; mt < 2; mt++) {
                int m_l = wv * 32 + mt * 16 + l15;
                int cb = (k2 * 4 + quad) ^ (m_l & 7);
                pf[mt] = *(const bf16x8*)&Ps[m_l * 64 + cb * 8];
            }
#pragma unroll
            for (int ht = 0; ht < 8; ht++) {
                int h = ht * 16 + l15;
                int cb = (k2 * 4 + quad) ^ (h & 7);
                bf16x8 vf = *(const bf16x8*)&Vt[h * 64 + cb * 8];
#pragma unroll
                for (int mt = 0; mt < 2; mt++)
                    Oacc[mt][ht] = __builtin_amdgcn_mfma_f32_16x16x32_bf16(pf[mt], vf, Oacc[mt][ht], 0, 0, 0);
            }
        }
    }

    // ---- epilogue ----
    if (quad == 0) {
        lArr[wv][0][l15] = lrow[0];
        lArr[wv][1][l15] = lrow[1];
    }
#pragma unroll
    for (int mt = 0; mt < 2; mt++) {
        f32x4 l4 = *(const f32x4*)&lArr[wv][mt][quad * 4];
        f32x4 inv;
        inv[0] = 1.0f / l4[0]; inv[1] = 1.0f / l4[1];
        inv[2] = 1.0f / l4[2]; inv[3] = 1.0f / l4[3];
        int mg0 = q0 + wv * 32 + mt * 16 + quad * 4;
        u16* dst0 = attnb + ((size_t)(b * Tdim + mg0)) * 2048 + n * 128 + l15;
#pragma unroll
        for (int ht = 0; ht < 8; ht++) {
#pragma unroll
            for (int r = 0; r < 4; r++)
                dst0[(size_t)r * 2048 + ht * 16] = f2bf(Oacc[mt][ht][r] * inv[r]);
        }
    }
}

extern "C" void kernel_launch(void* const* d_in, const int* in_sizes, int n_in,
                              void* d_out, int out_size, void* d_ws, size_t ws_size,
                              hipStream_t stream) {
    const float* Xq    = (const float*)d_in[0];
    const float* Xkv   = (const float*)d_in[1];
    const int*   qpos  = (const int*)d_in[2];
    const int*   kvpos = (const int*)d_in[3];
    const float* Wq    = (const float*)d_in[4];
    const float* Wk    = (const float*)d_in[5];
    const float* Wv    = (const float*)d_in[6];
    const float* Wo    = (const float*)d_in[7];
    float* out = (float*)d_out;

    char* w = (char*)d_ws;
    u16* xq_bf = (u16*)(w);                    // 16 MB
    u16* xkv_bf= (u16*)(w + (16u << 20));      // 16 MB
    u16* qraw  = (u16*)(w + (32u << 20));      // 16 MB (roped in place)
    u16* kraw  = (u16*)(w + (48u << 20));      //  4 MB (roped in place)
    u16* vt    = (u16*)(w + (52u << 20));      //  4 MB [(b*4+kvh)*128+h][2048]
    u16* wq_t  = (u16*)(w + (56u << 20));      //  8 MB
    u16* wk_t  = (u16*)(w + (64u << 20));      //  2 MB
    u16* wv_t  = (u16*)(w + (66u << 20));      //  2 MB
    u16* wo_t  = (u16*)(w + (68u << 20));      //  8 MB
    u16* attnb = (u16*)(w);                    // aliases xq_bf (dead by then)

    cvt_x<<<8192, 256, 0, stream>>>(Xq, Xkv, xq_bf, xkv_bf);
    cvt_w_t<<<dim3(32, 32), 256, 0, stream>>>(Wq, wq_t, 2048, 2048);
    cvt_w_t<<<dim3(8, 32),  256, 0, stream>>>(Wk, wk_t, 2048, 512);
    cvt_w_t<<<dim3(8, 32),  256, 0, stream>>>(Wv, wv_t, 2048, 512);
    cvt_w_t<<<dim3(32, 32), 256, 0, stream>>>(Wo, wo_t, 2048, 2048);
    qkv_gemm_bf<<<dim3(24, 32), 256, 0, stream>>>(xq_bf, xkv_bf, wq_t, wk_t, wv_t,
                                                  qraw, kraw, vt);
    rope_bf<<<5120, 256, 0, stream>>>(qraw, kraw, qpos, kvpos);
    flash_attn_v2<<<dim3(32, 16), 256, 0, stream>>>(qraw, kraw, vt, attnb);
    oproj_gemm_bf<<<dim3(16, 32), 256, 0, stream>>>(attnb, wo_t, out);
}